// Round 9
// baseline (395.695 us; speedup 1.0000x reference)
//
#include <hip/hip_runtime.h>
#include <hip/hip_bf16.h>

// Problem constants
#define N_ 64
#define C_ 64
#define T_ 300
#define V_ 25
#define K_ 3
#define TT 12             // t-values per block
#define NTILE 25          // T_/TT
#define NBLK 1600         // N_ * NTILE
#define XROW 384          // xs row pitch in elems: TT*32 (768B rows)
#define WP 72             // W-lds row pitch (144B, 16B-aligned b128 frag reads)
#define ATP 40            // At-lds row pitch (80B, 16B-aligned b128 frag reads)
#define NTHR 512          // 8 waves: (ob 0..3) x (t-half 0..1)
#define EPS_ 1e-5f

typedef __bf16 bf16_t;
typedef __bf16 bf16x4 __attribute__((ext_vector_type(4)));
typedef __bf16 bf16x8 __attribute__((ext_vector_type(8)));
typedef float f32x4 __attribute__((ext_vector_type(4)));
typedef float f32x4u __attribute__((ext_vector_type(4), aligned(4)));

static __device__ __forceinline__ bf16_t tobf(float f) { return (bf16_t)f; }
// element-index swizzle within a c-row (XOR of bits 3..5: keeps 4-runs contiguous)
static __device__ __forceinline__ int emask(int c) { return ((c & 3) << 3) | ((c & 8) << 2); }

// LDS overlay: W/A staging (prologue only) reuses the xs region.
union SmemU {
  struct { bf16_t W[3 * 64 * WP]; bf16_t At[3 * 32 * ATP]; } wa;   // 27.6KB + 7.7KB
  bf16_t xs[64 * XROW];                                            // 48KB
};

struct Frags {
  bf16x8 wfrag[6];
  bf16x8 afrag[3][2];
  int fK[4], fS5[4];
  float bs[4];
  int obase;
};

// ---- coalesced W/A global->LDS staging (bf16)
static __device__ __forceinline__ void stage_wa(
    const float* __restrict__ A, const float* __restrict__ W, SmemU& sm, int tid) {
  // W: 12288 floats = 3072 float4, [k][o][c] rows of 64
  for (int m = tid; m < 3072; m += NTHR) {
    f32x4 v4 = *(reinterpret_cast<const f32x4*>(W) + m);
    int f = m << 2;
    int k = f >> 12, o = (f >> 6) & 63, c = f & 63;
    bf16x4 h;
    h[0] = tobf(v4[0]); h[1] = tobf(v4[1]); h[2] = tobf(v4[2]); h[3] = tobf(v4[3]);
    *reinterpret_cast<bf16x4*>(&sm.wa.W[(k * 64 + o) * WP + c]) = h;
  }
  // A transposed + masked: At[k][w][v], v,w in [0,32), zeros outside 25x25
  for (int i = tid; i < 3072; i += NTHR) {
    int k = i >> 10, r = i & 1023, w = r >> 5, v = r & 31;
    float val = (v < V_ && w < V_) ? A[k * 625 + v * 25 + w] : 0.f;
    sm.wa.At[(k * 32 + w) * ATP + v] = tobf(val);
  }
}

static __device__ __forceinline__ void read_frags(
    const SmemU& sm, const float* __restrict__ b, int ob, int l15, int lg, Frags& F) {
  const int o = ob * 16 + l15;
  #pragma unroll
  for (int k = 0; k < 3; ++k)
    #pragma unroll
    for (int ch = 0; ch < 2; ++ch)
      F.wfrag[k * 2 + ch] =
          *reinterpret_cast<const bf16x8*>(&sm.wa.W[(k * 64 + o) * WP + ch * 32 + lg * 8]);
  #pragma unroll
  for (int k = 0; k < 3; ++k)
    #pragma unroll
    for (int wh = 0; wh < 2; ++wh)
      F.afrag[k][wh] =
          *reinterpret_cast<const bf16x8*>(&sm.wa.At[(k * 32 + wh * 16 + l15) * ATP + lg * 8]);
  // per-lane fragment LDS offsets. Permuted c-map (R3/R6/R7-verified):
  // frag q=(chalf,sub): c = chalf*32 + sub*4 + 8*(l15>>2) + (l15&3)
  const int crow = 8 * (l15 >> 2) + (l15 & 3);
  #pragma unroll
  for (int q = 0; q < 4; ++q) {
    int c = ((q >> 1) * 32) + ((q & 1) * 4) + crow;
    int em = emask(c);
    F.fK[q] = c * XROW + ((lg * 8) ^ (em & 24));
    F.fS5[q] = em & 32;
  }
  F.obase = ob * 16 + lg * 4;
  #pragma unroll
  for (int r = 0; r < 4; ++r)
    F.bs[r] = b[F.obase + r] + b[64 + F.obase + r] + b[128 + F.obase + r];
}

// ---- x staging: one f32x4u read + one b64 LDS write per (c,t,vblock).
static __device__ __forceinline__ void stage_x(
    const float* __restrict__ x, SmemU& sm, int n, int t0, int tid) {
  const float* xb = x + (size_t)n * 480000 + (size_t)t0 * 25;
  for (int i = tid; i < 64 * TT * 8; i += NTHR) {      // 12 iters
    int c = i / (TT * 8), r = i - c * (TT * 8);
    int t = r >> 3, vb = r & 7;                        // vb: 4-elem v-block
    bf16x4 h;
    if (vb < 6) {
      f32x4u v4 = *reinterpret_cast<const f32x4u*>(xb + (size_t)c * 7500 + t * 25 + vb * 4);
      h[0] = tobf(v4[0]); h[1] = tobf(v4[1]); h[2] = tobf(v4[2]); h[3] = tobf(v4[3]);
    } else if (vb == 6) {
      float s = xb[(size_t)c * 7500 + t * 25 + 24];
      h[0] = tobf(s); h[1] = tobf(0.f); h[2] = tobf(0.f); h[3] = tobf(0.f);
    } else {
      h[0] = tobf(0.f); h[1] = tobf(0.f); h[2] = tobf(0.f); h[3] = tobf(0.f);
    }
    *reinterpret_cast<bf16x4*>(&sm.xs[c * XROW + (((t << 5) + vb * 4) ^ emask(c))]) = h;
  }
}

// one t, one wh: register-chained stage-A -> stage-B (R3..R8-verified mapping)
static __device__ __forceinline__ void compute_wh(
    const bf16x8* xf, const Frags& F, int wh, f32x4& acc0, f32x4& acc1) {
  acc0 = f32x4{0.f, 0.f, 0.f, 0.f};
  acc1 = f32x4{0.f, 0.f, 0.f, 0.f};
  #pragma unroll
  for (int k = 0; k < 3; ++k) {
    #pragma unroll
    for (int ch = 0; ch < 2; ++ch) {
      f32x4 zero = {0.f, 0.f, 0.f, 0.f};
      f32x4 dP = __builtin_amdgcn_mfma_f32_16x16x32_bf16(xf[ch * 2 + 0], F.afrag[k][wh], zero, 0, 0, 0);
      f32x4 dQ = __builtin_amdgcn_mfma_f32_16x16x32_bf16(xf[ch * 2 + 1], F.afrag[k][wh], zero, 0, 0, 0);
      bf16x8 zf;
      zf[0] = tobf(dP[0]); zf[1] = tobf(dP[1]); zf[2] = tobf(dP[2]); zf[3] = tobf(dP[3]);
      zf[4] = tobf(dQ[0]); zf[5] = tobf(dQ[1]); zf[6] = tobf(dQ[2]); zf[7] = tobf(dQ[3]);
      if (ch == 0)
        acc0 = __builtin_amdgcn_mfma_f32_16x16x32_bf16(F.wfrag[k * 2 + ch], zf, acc0, 0, 0, 0);
      else
        acc1 = __builtin_amdgcn_mfma_f32_16x16x32_bf16(F.wfrag[k * 2 + ch], zf, acc1, 0, 0, 0);
    }
  }
}

// ---------------------------------------------------------------------------
// K1: compute y (stored to d_out staging) + per-block channel partials.
// 8 waves: wave (ob, th) -> o-block ob, t in [th*6, th*6+6).
// ---------------------------------------------------------------------------
__global__ __launch_bounds__(NTHR, 6) void k1_compute(
    const float* __restrict__ x, const float* __restrict__ A,
    const float* __restrict__ W, const float* __restrict__ b,
    float* __restrict__ y, float* __restrict__ part) {
  __shared__ __align__(16) SmemU sm;
  __shared__ float stats2[2][2][64];   // [sum|sq][t-half][o]

  const int bid = (blockIdx.x & 7) * (NBLK / 8) + (blockIdx.x >> 3);  // bijective
  const int n = bid / NTILE;
  const int t0 = (bid - n * NTILE) * TT;
  const int tid = threadIdx.x;
  const int lane = tid & 63;
  const int wv = tid >> 6;        // 0..7
  const int ob = wv & 3;          // o-block
  const int th = wv >> 2;         // t-half
  const int l15 = lane & 15;
  const int lg = lane >> 4;

  stage_wa(A, W, sm, tid);
  __syncthreads();
  Frags F;
  read_frags(sm, b, ob, l15, lg, F);
  __syncthreads();                 // all frag reads done before xs overwrite
  stage_x(x, sm, n, t0, tid);
  __syncthreads();

  float lsum[4] = {0.f, 0.f, 0.f, 0.f}, lsq[4] = {0.f, 0.f, 0.f, 0.f};
  const int w_lo = l15, w_hi = 16 + l15;
  float* yb = y + (size_t)n * 480000 + (size_t)t0 * 25;

  #pragma unroll 2
  for (int tl = 0; tl < 6; ++tl) {
    const int t = th * 6 + tl;
    bf16x8 xf[4];
    #pragma unroll
    for (int q = 0; q < 4; ++q)
      xf[q] = *reinterpret_cast<const bf16x8*>(sm.xs + F.fK[q] + ((t << 5) ^ F.fS5[q]));
    #pragma unroll
    for (int wh = 0; wh < 2; ++wh) {
      f32x4 acc0, acc1;
      compute_wh(xf, F, wh, acc0, acc1);
      const int w = wh ? w_hi : w_lo;
      if (w < V_) {
        #pragma unroll
        for (int r = 0; r < 4; ++r) {
          float val = acc0[r] + acc1[r] + F.bs[r];
          lsum[r] += val;
          lsq[r] += val * val;
          yb[(size_t)(F.obase + r) * 7500 + t * 25 + w] = val;
        }
      }
    }
  }

  // reduce across the 16 lanes (l15) that share the same 4 o-rows
  #pragma unroll
  for (int d = 1; d < 16; d <<= 1) {
    #pragma unroll
    for (int r = 0; r < 4; ++r) {
      lsum[r] += __shfl_xor(lsum[r], d);
      lsq[r]  += __shfl_xor(lsq[r], d);
    }
  }
  if (l15 == 0) {
    #pragma unroll
    for (int r = 0; r < 4; ++r) {
      stats2[0][th][F.obase + r] = lsum[r];
      stats2[1][th][F.obase + r] = lsq[r];
    }
  }
  __syncthreads();
  if (tid < 128)
    part[(size_t)bid * 128 + tid] =
        stats2[tid >> 6][0][tid & 63] + stats2[tid >> 6][1][tid & 63];
}

// ---------------------------------------------------------------------------
// K2: reduce partials -> per-channel scale/shift
// ---------------------------------------------------------------------------
__global__ __launch_bounds__(256) void k2_stats(
    const float* __restrict__ part,
    const float* __restrict__ gamma, const float* __restrict__ beta,
    float* __restrict__ ss) {
  const int o = blockIdx.x;
  const int tid = threadIdx.x;
  double s = 0.0, q = 0.0;
  for (int i = tid; i < NBLK; i += 256) {
    s += (double)part[(size_t)i * 128 + o];
    q += (double)part[(size_t)i * 128 + 64 + o];
  }
  __shared__ double sd[256], qd[256];
  sd[tid] = s; qd[tid] = q;
  __syncthreads();
  for (int step = 128; step > 0; step >>= 1) {
    if (tid < step) { sd[tid] += sd[tid + step]; qd[tid] += qd[tid + step]; }
    __syncthreads();
  }
  if (tid == 0) {
    const double cnt = 480000.0;
    double mean = sd[0] / cnt;
    double var = qd[0] / cnt - mean * mean;
    float inv = rsqrtf((float)var + EPS_);
    float sc = gamma[o] * inv;
    float sh = beta[o] - (float)mean * sc;
    ss[2 * o] = sc;
    ss[2 * o + 1] = sh;
  }
}

// ---------------------------------------------------------------------------
// K3: out = relu(scale[c]*y + shift[c] + x), in place on d_out (y staged there).
// One block per (n,c) plane: 7500 floats = 1875 float4, uniform scale/shift.
// ---------------------------------------------------------------------------
__global__ __launch_bounds__(256) void k3_finish(
    const float* __restrict__ x, const float* __restrict__ ss,
    float* __restrict__ y) {
  const int p = blockIdx.x;       // 0..4095 = n*64 + c
  const int c = p & 63;
  const float sc = ss[2 * c];
  const float sh = ss[2 * c + 1];
  const float4* xv = reinterpret_cast<const float4*>(x + (size_t)p * 7500);
  float4* yv = reinterpret_cast<float4*>(y + (size_t)p * 7500);
  for (int i = threadIdx.x; i < 1875; i += 256) {
    float4 a = yv[i];
    float4 b4 = xv[i];
    float4 o;
    o.x = fmaxf(sc * a.x + sh + b4.x, 0.f);
    o.y = fmaxf(sc * a.y + sh + b4.y, 0.f);
    o.z = fmaxf(sc * a.z + sh + b4.z, 0.f);
    o.w = fmaxf(sc * a.w + sh + b4.w, 0.f);
    yv[i] = o;
  }
}

extern "C" void kernel_launch(void* const* d_in, const int* in_sizes, int n_in,
                              void* d_out, int out_size, void* d_ws, size_t ws_size,
                              hipStream_t stream) {
  const float* x     = (const float*)d_in[0];
  const float* A     = (const float*)d_in[1];
  const float* W     = (const float*)d_in[2];
  const float* b     = (const float*)d_in[3];
  const float* gamma = (const float*)d_in[4];
  const float* beta  = (const float*)d_in[5];
  float* y = (float*)d_out;                  // stage y in d_out, finish in place

  float* part = (float*)d_ws;                // NBLK*128 floats (contiguous per block)
  float* ss   = part + (size_t)NBLK * 128;   // 128 floats

  k1_compute<<<NBLK, NTHR, 0, stream>>>(x, A, W, b, y, part);
  k2_stats<<<64, 256, 0, stream>>>(part, gamma, beta, ss);
  k3_finish<<<4096, 256, 0, stream>>>(x, ss, y);
}

// Round 10
// 145.403 us; speedup vs baseline: 2.7214x; 2.7214x over previous
//
#include <hip/hip_runtime.h>
#include <hip/hip_bf16.h>

// Problem constants
#define N_ 64
#define C_ 64
#define T_ 300
#define V_ 25
#define K_ 3
#define TT 12             // t-values per block
#define NTILE 25          // T_/TT
#define NBLK 1600         // N_ * NTILE
#define XROW 384          // xs row pitch in elems: TT*32 (768B rows)
#define WP 72             // W-lds row pitch (144B, 16B-aligned b128 frag reads)
#define ATP 40            // At-lds row pitch (80B, 16B-aligned b128 frag reads)
#define NTHR 512          // 8 waves: (ob 0..3) x (t-half 0..1)
#define EPS_ 1e-5f

typedef __bf16 bf16_t;
typedef __bf16 bf16x4 __attribute__((ext_vector_type(4)));
typedef __bf16 bf16x8 __attribute__((ext_vector_type(8)));
typedef float f32x4 __attribute__((ext_vector_type(4)));
typedef float f32x4u __attribute__((ext_vector_type(4), aligned(4)));

static __device__ __forceinline__ bf16_t tobf(float f) { return (bf16_t)f; }
// element-index swizzle within a c-row (XOR of bits 3..5: keeps 4-runs contiguous)
static __device__ __forceinline__ int emask(int c) { return ((c & 3) << 3) | ((c & 8) << 2); }

// LDS overlay: W/A staging (prologue only) reuses the xs region.
union SmemU {
  struct { bf16_t W[3 * 64 * WP]; bf16_t At[3 * 32 * ATP]; } wa;   // 27.6KB + 7.7KB
  bf16_t xs[64 * XROW];                                            // 48KB
};

struct Frags {
  bf16x8 wfrag[6];
  bf16x8 afrag[3][2];
  int fK[4], fS5[4];
  float bs[4];
  int obase;
};

// ---- coalesced W/A global->LDS staging (bf16)
static __device__ __forceinline__ void stage_wa(
    const float* __restrict__ A, const float* __restrict__ W, SmemU& sm, int tid) {
  // W: 12288 floats = 3072 float4, [k][o][c] rows of 64
  for (int m = tid; m < 3072; m += NTHR) {
    f32x4 v4 = *(reinterpret_cast<const f32x4*>(W) + m);
    int f = m << 2;
    int k = f >> 12, o = (f >> 6) & 63, c = f & 63;
    bf16x4 h;
    h[0] = tobf(v4[0]); h[1] = tobf(v4[1]); h[2] = tobf(v4[2]); h[3] = tobf(v4[3]);
    *reinterpret_cast<bf16x4*>(&sm.wa.W[(k * 64 + o) * WP + c]) = h;
  }
  // A transposed + masked: At[k][w][v], v,w in [0,32), zeros outside 25x25
  for (int i = tid; i < 3072; i += NTHR) {
    int k = i >> 10, r = i & 1023, w = r >> 5, v = r & 31;
    float val = (v < V_ && w < V_) ? A[k * 625 + v * 25 + w] : 0.f;
    sm.wa.At[(k * 32 + w) * ATP + v] = tobf(val);
  }
}

static __device__ __forceinline__ void read_frags(
    const SmemU& sm, const float* __restrict__ b, int ob, int l15, int lg, Frags& F) {
  const int o = ob * 16 + l15;
  #pragma unroll
  for (int k = 0; k < 3; ++k)
    #pragma unroll
    for (int ch = 0; ch < 2; ++ch)
      F.wfrag[k * 2 + ch] =
          *reinterpret_cast<const bf16x8*>(&sm.wa.W[(k * 64 + o) * WP + ch * 32 + lg * 8]);
  #pragma unroll
  for (int k = 0; k < 3; ++k)
    #pragma unroll
    for (int wh = 0; wh < 2; ++wh)
      F.afrag[k][wh] =
          *reinterpret_cast<const bf16x8*>(&sm.wa.At[(k * 32 + wh * 16 + l15) * ATP + lg * 8]);
  // per-lane fragment LDS offsets. Permuted c-map (R3/R6/R7-verified):
  // frag q=(chalf,sub): c = chalf*32 + sub*4 + 8*(l15>>2) + (l15&3)
  const int crow = 8 * (l15 >> 2) + (l15 & 3);
  #pragma unroll
  for (int q = 0; q < 4; ++q) {
    int c = ((q >> 1) * 32) + ((q & 1) * 4) + crow;
    int em = emask(c);
    F.fK[q] = c * XROW + ((lg * 8) ^ (em & 24));
    F.fS5[q] = em & 32;
  }
  F.obase = ob * 16 + lg * 4;
  #pragma unroll
  for (int r = 0; r < 4; ++r)
    F.bs[r] = b[F.obase + r] + b[64 + F.obase + r] + b[128 + F.obase + r];
}

// ---- x staging: 512 threads = 64 c-rows x 8 v-blocks; pure bit-op indexing.
// One f32x4u read + one b64 LDS write per (c,t,vblock). Pads written as zeros.
static __device__ __forceinline__ void stage_x(
    const float* __restrict__ x, SmemU& sm, int n, int t0, int tid) {
  const int c = tid >> 3, vb = tid & 7;
  const int em = emask(c);
  const float* xr = x + (size_t)n * 480000 + (size_t)c * 7500 + (size_t)t0 * 25;
  bf16_t* xsr = &sm.xs[c * XROW];
  #pragma unroll
  for (int t = 0; t < TT; ++t) {
    bf16x4 h;
    if (vb < 6) {
      f32x4u v4 = *reinterpret_cast<const f32x4u*>(xr + t * 25 + vb * 4);
      h[0] = tobf(v4[0]); h[1] = tobf(v4[1]); h[2] = tobf(v4[2]); h[3] = tobf(v4[3]);
    } else if (vb == 6) {
      float s = xr[t * 25 + 24];
      h[0] = tobf(s); h[1] = tobf(0.f); h[2] = tobf(0.f); h[3] = tobf(0.f);
    } else {
      h[0] = tobf(0.f); h[1] = tobf(0.f); h[2] = tobf(0.f); h[3] = tobf(0.f);
    }
    *reinterpret_cast<bf16x4*>(&xsr[(((t << 5) + vb * 4) ^ em)]) = h;
  }
}

// one t, one wh: register-chained stage-A -> stage-B (R3..R9-verified mapping)
static __device__ __forceinline__ void compute_wh(
    const bf16x8* xf, const Frags& F, int wh, f32x4& acc0, f32x4& acc1) {
  acc0 = f32x4{0.f, 0.f, 0.f, 0.f};
  acc1 = f32x4{0.f, 0.f, 0.f, 0.f};
  #pragma unroll
  for (int k = 0; k < 3; ++k) {
    #pragma unroll
    for (int ch = 0; ch < 2; ++ch) {
      f32x4 zero = {0.f, 0.f, 0.f, 0.f};
      f32x4 dP = __builtin_amdgcn_mfma_f32_16x16x32_bf16(xf[ch * 2 + 0], F.afrag[k][wh], zero, 0, 0, 0);
      f32x4 dQ = __builtin_amdgcn_mfma_f32_16x16x32_bf16(xf[ch * 2 + 1], F.afrag[k][wh], zero, 0, 0, 0);
      bf16x8 zf;
      zf[0] = tobf(dP[0]); zf[1] = tobf(dP[1]); zf[2] = tobf(dP[2]); zf[3] = tobf(dP[3]);
      zf[4] = tobf(dQ[0]); zf[5] = tobf(dQ[1]); zf[6] = tobf(dQ[2]); zf[7] = tobf(dQ[3]);
      if (ch == 0)
        acc0 = __builtin_amdgcn_mfma_f32_16x16x32_bf16(F.wfrag[k * 2 + ch], zf, acc0, 0, 0, 0);
      else
        acc1 = __builtin_amdgcn_mfma_f32_16x16x32_bf16(F.wfrag[k * 2 + ch], zf, acc1, 0, 0, 0);
    }
  }
}

// ---------------------------------------------------------------------------
// K1: compute y (stored to d_out staging) + per-block channel partials.
// 8 waves: wave (ob, th) -> o-block ob, t in [th*6, th*6+6).
// launch_bounds(512,4): VGPR cap 128 -- (512,6) forced cap<natural and spilled
// ~960MB scratch traffic in R9 (FETCH 517MB / WRITE 608MB signature).
// ---------------------------------------------------------------------------
__global__ __launch_bounds__(NTHR, 4) void k1_compute(
    const float* __restrict__ x, const float* __restrict__ A,
    const float* __restrict__ W, const float* __restrict__ b,
    float* __restrict__ y, float* __restrict__ part) {
  __shared__ __align__(16) SmemU sm;
  __shared__ float stats2[2][2][64];   // [sum|sq][t-half][o]

  const int bid = (blockIdx.x & 7) * (NBLK / 8) + (blockIdx.x >> 3);  // bijective
  const int n = bid / NTILE;
  const int t0 = (bid - n * NTILE) * TT;
  const int tid = threadIdx.x;
  const int lane = tid & 63;
  const int wv = tid >> 6;        // 0..7
  const int ob = wv & 3;          // o-block
  const int th = wv >> 2;         // t-half
  const int l15 = lane & 15;
  const int lg = lane >> 4;

  stage_wa(A, W, sm, tid);
  __syncthreads();
  Frags F;
  read_frags(sm, b, ob, l15, lg, F);
  __syncthreads();                 // all frag reads done before xs overwrite
  stage_x(x, sm, n, t0, tid);
  __syncthreads();

  float lsum[4] = {0.f, 0.f, 0.f, 0.f}, lsq[4] = {0.f, 0.f, 0.f, 0.f};
  const int w_lo = l15, w_hi = 16 + l15;
  float* yb = y + (size_t)n * 480000 + (size_t)t0 * 25;

  #pragma unroll 2
  for (int tl = 0; tl < 6; ++tl) {
    const int t = th * 6 + tl;
    bf16x8 xf[4];
    #pragma unroll
    for (int q = 0; q < 4; ++q)
      xf[q] = *reinterpret_cast<const bf16x8*>(sm.xs + F.fK[q] + ((t << 5) ^ F.fS5[q]));
    #pragma unroll
    for (int wh = 0; wh < 2; ++wh) {
      f32x4 acc0, acc1;
      compute_wh(xf, F, wh, acc0, acc1);
      const int w = wh ? w_hi : w_lo;
      if (w < V_) {
        #pragma unroll
        for (int r = 0; r < 4; ++r) {
          float val = acc0[r] + acc1[r] + F.bs[r];
          lsum[r] += val;
          lsq[r] += val * val;
          yb[(size_t)(F.obase + r) * 7500 + t * 25 + w] = val;
        }
      }
    }
  }

  // reduce across the 16 lanes (l15) that share the same 4 o-rows
  #pragma unroll
  for (int d = 1; d < 16; d <<= 1) {
    #pragma unroll
    for (int r = 0; r < 4; ++r) {
      lsum[r] += __shfl_xor(lsum[r], d);
      lsq[r]  += __shfl_xor(lsq[r], d);
    }
  }
  if (l15 == 0) {
    #pragma unroll
    for (int r = 0; r < 4; ++r) {
      stats2[0][th][F.obase + r] = lsum[r];
      stats2[1][th][F.obase + r] = lsq[r];
    }
  }
  __syncthreads();
  if (tid < 128)
    part[(size_t)bid * 128 + tid] =
        stats2[tid >> 6][0][tid & 63] + stats2[tid >> 6][1][tid & 63];
}

// ---------------------------------------------------------------------------
// K2: reduce partials -> per-channel scale/shift
// ---------------------------------------------------------------------------
__global__ __launch_bounds__(256) void k2_stats(
    const float* __restrict__ part,
    const float* __restrict__ gamma, const float* __restrict__ beta,
    float* __restrict__ ss) {
  const int o = blockIdx.x;
  const int tid = threadIdx.x;
  double s = 0.0, q = 0.0;
  for (int i = tid; i < NBLK; i += 256) {
    s += (double)part[(size_t)i * 128 + o];
    q += (double)part[(size_t)i * 128 + 64 + o];
  }
  __shared__ double sd[256], qd[256];
  sd[tid] = s; qd[tid] = q;
  __syncthreads();
  for (int step = 128; step > 0; step >>= 1) {
    if (tid < step) { sd[tid] += sd[tid + step]; qd[tid] += qd[tid + step]; }
    __syncthreads();
  }
  if (tid == 0) {
    const double cnt = 480000.0;
    double mean = sd[0] / cnt;
    double var = qd[0] / cnt - mean * mean;
    float inv = rsqrtf((float)var + EPS_);
    float sc = gamma[o] * inv;
    float sh = beta[o] - (float)mean * sc;
    ss[2 * o] = sc;
    ss[2 * o + 1] = sh;
  }
}

// ---------------------------------------------------------------------------
// K3: out = relu(scale[c]*y + shift[c] + x), in place on d_out (y staged there).
// One block per (n,c) plane: 7500 floats = 1875 float4, uniform scale/shift.
// ---------------------------------------------------------------------------
__global__ __launch_bounds__(256) void k3_finish(
    const float* __restrict__ x, const float* __restrict__ ss,
    float* __restrict__ y) {
  const int p = blockIdx.x;       // 0..4095 = n*64 + c
  const int c = p & 63;
  const float sc = ss[2 * c];
  const float sh = ss[2 * c + 1];
  const float4* xv = reinterpret_cast<const float4*>(x + (size_t)p * 7500);
  float4* yv = reinterpret_cast<float4*>(y + (size_t)p * 7500);
  for (int i = threadIdx.x; i < 1875; i += 256) {
    float4 a = yv[i];
    float4 b4 = xv[i];
    float4 o;
    o.x = fmaxf(sc * a.x + sh + b4.x, 0.f);
    o.y = fmaxf(sc * a.y + sh + b4.y, 0.f);
    o.z = fmaxf(sc * a.z + sh + b4.z, 0.f);
    o.w = fmaxf(sc * a.w + sh + b4.w, 0.f);
    yv[i] = o;
  }
}

extern "C" void kernel_launch(void* const* d_in, const int* in_sizes, int n_in,
                              void* d_out, int out_size, void* d_ws, size_t ws_size,
                              hipStream_t stream) {
  const float* x     = (const float*)d_in[0];
  const float* A     = (const float*)d_in[1];
  const float* W     = (const float*)d_in[2];
  const float* b     = (const float*)d_in[3];
  const float* gamma = (const float*)d_in[4];
  const float* beta  = (const float*)d_in[5];
  float* y = (float*)d_out;                  // stage y in d_out, finish in place

  float* part = (float*)d_ws;                // NBLK*128 floats (contiguous per block)
  float* ss   = part + (size_t)NBLK * 128;   // 128 floats

  k1_compute<<<NBLK, NTHR, 0, stream>>>(x, A, W, b, y, part);
  k2_stats<<<64, 256, 0, stream>>>(part, gamma, beta, ss);
  k3_finish<<<4096, 256, 0, stream>>>(x, ss, y);
}

// Round 11
// 141.995 us; speedup vs baseline: 2.7867x; 1.0240x over previous
//
#include <hip/hip_runtime.h>
#include <hip/hip_bf16.h>

// Problem constants
#define N_ 64
#define C_ 64
#define T_ 300
#define V_ 25
#define K_ 3
#define TT 12             // t-values per tile
#define NTILE 25          // T_/TT
#define NBLK 1600         // total tiles = N_ * NTILE
#define NPERS 768         // persistent blocks = 3/CU x 256 CU (all resident)
#define XROW 384          // xs row pitch in elems: TT*32 (768B rows)
#define WP 72             // W-lds row pitch (144B, 16B-aligned b128 frag reads)
#define ATP 40            // At-lds row pitch (80B, 16B-aligned b128 frag reads)
#define NTHR 512          // 8 waves: (ob 0..3) x (t-half 0..1)
#define EPS_ 1e-5f

typedef __bf16 bf16_t;
typedef __bf16 bf16x4 __attribute__((ext_vector_type(4)));
typedef __bf16 bf16x8 __attribute__((ext_vector_type(8)));
typedef float f32x4 __attribute__((ext_vector_type(4)));
typedef float f32x4u __attribute__((ext_vector_type(4), aligned(4)));

static __device__ __forceinline__ bf16_t tobf(float f) { return (bf16_t)f; }
// element-index swizzle within a c-row (XOR of bits 3..5: keeps 4-runs contiguous)
static __device__ __forceinline__ int emask(int c) { return ((c & 3) << 3) | ((c & 8) << 2); }

// LDS overlay: W/A staging (prologue only; frags move to registers) reuses xs.
union SmemU {
  struct { bf16_t W[3 * 64 * WP]; bf16_t At[3 * 32 * ATP]; } wa;   // 27.6KB + 7.7KB
  bf16_t xs[64 * XROW];                                            // 48KB
};

struct Frags {
  bf16x8 wfrag[6];
  bf16x8 afrag[3][2];
  int fK[4], fS5[4];
  float bs[4];
  int obase;
};

// ---- coalesced W/A global->LDS staging (bf16)
static __device__ __forceinline__ void stage_wa(
    const float* __restrict__ A, const float* __restrict__ W, SmemU& sm, int tid) {
  // W: 12288 floats = 3072 float4, [k][o][c] rows of 64
  for (int m = tid; m < 3072; m += NTHR) {
    f32x4 v4 = *(reinterpret_cast<const f32x4*>(W) + m);
    int f = m << 2;
    int k = f >> 12, o = (f >> 6) & 63, c = f & 63;
    bf16x4 h;
    h[0] = tobf(v4[0]); h[1] = tobf(v4[1]); h[2] = tobf(v4[2]); h[3] = tobf(v4[3]);
    *reinterpret_cast<bf16x4*>(&sm.wa.W[(k * 64 + o) * WP + c]) = h;
  }
  // A transposed + masked: At[k][w][v], v,w in [0,32), zeros outside 25x25
  for (int i = tid; i < 3072; i += NTHR) {
    int k = i >> 10, r = i & 1023, w = r >> 5, v = r & 31;
    float val = (v < V_ && w < V_) ? A[k * 625 + v * 25 + w] : 0.f;
    sm.wa.At[(k * 32 + w) * ATP + v] = tobf(val);
  }
}

static __device__ __forceinline__ void read_frags(
    const SmemU& sm, const float* __restrict__ b, int ob, int l15, int lg, Frags& F) {
  const int o = ob * 16 + l15;
  #pragma unroll
  for (int k = 0; k < 3; ++k)
    #pragma unroll
    for (int ch = 0; ch < 2; ++ch)
      F.wfrag[k * 2 + ch] =
          *reinterpret_cast<const bf16x8*>(&sm.wa.W[(k * 64 + o) * WP + ch * 32 + lg * 8]);
  #pragma unroll
  for (int k = 0; k < 3; ++k)
    #pragma unroll
    for (int wh = 0; wh < 2; ++wh)
      F.afrag[k][wh] =
          *reinterpret_cast<const bf16x8*>(&sm.wa.At[(k * 32 + wh * 16 + l15) * ATP + lg * 8]);
  // per-lane fragment LDS offsets. Permuted c-map (R3..R10-verified):
  // frag q=(chalf,sub): c = chalf*32 + sub*4 + 8*(l15>>2) + (l15&3)
  const int crow = 8 * (l15 >> 2) + (l15 & 3);
  #pragma unroll
  for (int q = 0; q < 4; ++q) {
    int c = ((q >> 1) * 32) + ((q & 1) * 4) + crow;
    int em = emask(c);
    F.fK[q] = c * XROW + ((lg * 8) ^ (em & 24));
    F.fS5[q] = em & 32;
  }
  F.obase = ob * 16 + lg * 4;
  #pragma unroll
  for (int r = 0; r < 4; ++r)
    F.bs[r] = b[F.obase + r] + b[64 + F.obase + r] + b[128 + F.obase + r];
}

// ---- x staging: 512 threads = 64 c-rows x 8 v-blocks; pure bit-op indexing.
static __device__ __forceinline__ void stage_x(
    const float* __restrict__ x, SmemU& sm, int n, int t0, int tid) {
  const int c = tid >> 3, vb = tid & 7;
  const int em = emask(c);
  const float* xr = x + (size_t)n * 480000 + (size_t)c * 7500 + (size_t)t0 * 25;
  bf16_t* xsr = &sm.xs[c * XROW];
  #pragma unroll
  for (int t = 0; t < TT; ++t) {
    bf16x4 h;
    if (vb < 6) {
      f32x4u v4 = *reinterpret_cast<const f32x4u*>(xr + t * 25 + vb * 4);
      h[0] = tobf(v4[0]); h[1] = tobf(v4[1]); h[2] = tobf(v4[2]); h[3] = tobf(v4[3]);
    } else if (vb == 6) {
      float s = xr[t * 25 + 24];
      h[0] = tobf(s); h[1] = tobf(0.f); h[2] = tobf(0.f); h[3] = tobf(0.f);
    } else {
      h[0] = tobf(0.f); h[1] = tobf(0.f); h[2] = tobf(0.f); h[3] = tobf(0.f);
    }
    *reinterpret_cast<bf16x4*>(&xsr[(((t << 5) + vb * 4) ^ em)]) = h;
  }
}

// one t, one wh: register-chained stage-A -> stage-B (R3..R10-verified mapping)
static __device__ __forceinline__ void compute_wh(
    const bf16x8* xf, const Frags& F, int wh, f32x4& acc0, f32x4& acc1) {
  acc0 = f32x4{0.f, 0.f, 0.f, 0.f};
  acc1 = f32x4{0.f, 0.f, 0.f, 0.f};
  #pragma unroll
  for (int k = 0; k < 3; ++k) {
    #pragma unroll
    for (int ch = 0; ch < 2; ++ch) {
      f32x4 zero = {0.f, 0.f, 0.f, 0.f};
      f32x4 dP = __builtin_amdgcn_mfma_f32_16x16x32_bf16(xf[ch * 2 + 0], F.afrag[k][wh], zero, 0, 0, 0);
      f32x4 dQ = __builtin_amdgcn_mfma_f32_16x16x32_bf16(xf[ch * 2 + 1], F.afrag[k][wh], zero, 0, 0, 0);
      bf16x8 zf;
      zf[0] = tobf(dP[0]); zf[1] = tobf(dP[1]); zf[2] = tobf(dP[2]); zf[3] = tobf(dP[3]);
      zf[4] = tobf(dQ[0]); zf[5] = tobf(dQ[1]); zf[6] = tobf(dQ[2]); zf[7] = tobf(dQ[3]);
      if (ch == 0)
        acc0 = __builtin_amdgcn_mfma_f32_16x16x32_bf16(F.wfrag[k * 2 + ch], zf, acc0, 0, 0, 0);
      else
        acc1 = __builtin_amdgcn_mfma_f32_16x16x32_bf16(F.wfrag[k * 2 + ch], zf, acc1, 0, 0, 0);
    }
  }
}

// ---------------------------------------------------------------------------
// K1: PERSISTENT blocks + atomic tile queue. Prologue (W/A stage + frag read)
// once per block; then loop tiles: stage_x -> compute -> y store + partials.
// Deterministic: per-tile outputs and part[tile] don't depend on which block
// processes the tile; k2 reduces in fixed order.
// ---------------------------------------------------------------------------
__global__ __launch_bounds__(NTHR, 4) void k1_compute(
    const float* __restrict__ x, const float* __restrict__ A,
    const float* __restrict__ W, const float* __restrict__ b,
    float* __restrict__ y, float* __restrict__ part, int* __restrict__ counter) {
  __shared__ __align__(16) SmemU sm;
  __shared__ float stats2[2][2][64];   // [sum|sq][t-half][o]
  __shared__ int tile_s;

  const int tid = threadIdx.x;
  const int lane = tid & 63;
  const int wv = tid >> 6;        // 0..7
  const int ob = wv & 3;          // o-block
  const int th = wv >> 2;         // t-half
  const int l15 = lane & 15;
  const int lg = lane >> 4;

  stage_wa(A, W, sm, tid);
  __syncthreads();
  Frags F;
  read_frags(sm, b, ob, l15, lg, F);

  const int w_lo = l15, w_hi = 16 + l15;

  for (;;) {
    if (tid == 0) tile_s = atomicAdd(counter, 1);
    __syncthreads();              // tile_s visible; prior xs reads/frag reads done
    const int tile = tile_s;
    if (tile >= NBLK) break;
    const int n = tile / NTILE;
    const int t0 = (tile - n * NTILE) * TT;

    stage_x(x, sm, n, t0, tid);
    __syncthreads();

    float lsum[4] = {0.f, 0.f, 0.f, 0.f}, lsq[4] = {0.f, 0.f, 0.f, 0.f};
    float* yb = y + (size_t)n * 480000 + (size_t)t0 * 25;

    #pragma unroll 2
    for (int tl = 0; tl < 6; ++tl) {
      const int t = th * 6 + tl;
      bf16x8 xf[4];
      #pragma unroll
      for (int q = 0; q < 4; ++q)
        xf[q] = *reinterpret_cast<const bf16x8*>(sm.xs + F.fK[q] + ((t << 5) ^ F.fS5[q]));
      #pragma unroll
      for (int wh = 0; wh < 2; ++wh) {
        f32x4 acc0, acc1;
        compute_wh(xf, F, wh, acc0, acc1);
        const int w = wh ? w_hi : w_lo;
        if (w < V_) {
          #pragma unroll
          for (int r = 0; r < 4; ++r) {
            float val = acc0[r] + acc1[r] + F.bs[r];
            lsum[r] += val;
            lsq[r] += val * val;
            yb[(size_t)(F.obase + r) * 7500 + t * 25 + w] = val;
          }
        }
      }
    }

    // reduce across the 16 lanes (l15) that share the same 4 o-rows
    #pragma unroll
    for (int d = 1; d < 16; d <<= 1) {
      #pragma unroll
      for (int r = 0; r < 4; ++r) {
        lsum[r] += __shfl_xor(lsum[r], d);
        lsq[r]  += __shfl_xor(lsq[r], d);
      }
    }
    if (l15 == 0) {
      #pragma unroll
      for (int r = 0; r < 4; ++r) {
        stats2[0][th][F.obase + r] = lsum[r];
        stats2[1][th][F.obase + r] = lsq[r];
      }
    }
    __syncthreads();
    if (tid < 128)
      part[(size_t)tile * 128 + tid] =
          stats2[tid >> 6][0][tid & 63] + stats2[tid >> 6][1][tid & 63];
  }
}

// ---------------------------------------------------------------------------
// K2: reduce partials -> per-channel scale/shift
// ---------------------------------------------------------------------------
__global__ __launch_bounds__(256) void k2_stats(
    const float* __restrict__ part,
    const float* __restrict__ gamma, const float* __restrict__ beta,
    float* __restrict__ ss) {
  const int o = blockIdx.x;
  const int tid = threadIdx.x;
  double s = 0.0, q = 0.0;
  for (int i = tid; i < NBLK; i += 256) {
    s += (double)part[(size_t)i * 128 + o];
    q += (double)part[(size_t)i * 128 + 64 + o];
  }
  __shared__ double sd[256], qd[256];
  sd[tid] = s; qd[tid] = q;
  __syncthreads();
  for (int step = 128; step > 0; step >>= 1) {
    if (tid < step) { sd[tid] += sd[tid + step]; qd[tid] += qd[tid + step]; }
    __syncthreads();
  }
  if (tid == 0) {
    const double cnt = 480000.0;
    double mean = sd[0] / cnt;
    double var = qd[0] / cnt - mean * mean;
    float inv = rsqrtf((float)var + EPS_);
    float sc = gamma[o] * inv;
    float sh = beta[o] - (float)mean * sc;
    ss[2 * o] = sc;
    ss[2 * o + 1] = sh;
  }
}

// ---------------------------------------------------------------------------
// K3: out = relu(scale[c]*y + shift[c] + x), in place on d_out (y staged there).
// ---------------------------------------------------------------------------
__global__ __launch_bounds__(256) void k3_finish(
    const float* __restrict__ x, const float* __restrict__ ss,
    float* __restrict__ y) {
  const int p = blockIdx.x;       // 0..4095 = n*64 + c
  const int c = p & 63;
  const float sc = ss[2 * c];
  const float sh = ss[2 * c + 1];
  const float4* xv = reinterpret_cast<const float4*>(x + (size_t)p * 7500);
  float4* yv = reinterpret_cast<float4*>(y + (size_t)p * 7500);
  for (int i = threadIdx.x; i < 1875; i += 256) {
    float4 a = yv[i];
    float4 b4 = xv[i];
    float4 o;
    o.x = fmaxf(sc * a.x + sh + b4.x, 0.f);
    o.y = fmaxf(sc * a.y + sh + b4.y, 0.f);
    o.z = fmaxf(sc * a.z + sh + b4.z, 0.f);
    o.w = fmaxf(sc * a.w + sh + b4.w, 0.f);
    yv[i] = o;
  }
}

extern "C" void kernel_launch(void* const* d_in, const int* in_sizes, int n_in,
                              void* d_out, int out_size, void* d_ws, size_t ws_size,
                              hipStream_t stream) {
  const float* x     = (const float*)d_in[0];
  const float* A     = (const float*)d_in[1];
  const float* W     = (const float*)d_in[2];
  const float* b     = (const float*)d_in[3];
  const float* gamma = (const float*)d_in[4];
  const float* beta  = (const float*)d_in[5];
  float* y = (float*)d_out;                  // stage y in d_out, finish in place

  int*   counter = (int*)d_ws;               // tile queue head (reset each launch)
  float* part = (float*)d_ws + 64;           // NBLK*128 floats (contiguous per tile)
  float* ss   = part + (size_t)NBLK * 128;   // 128 floats

  hipMemsetAsync(counter, 0, sizeof(int), stream);
  k1_compute<<<NPERS, NTHR, 0, stream>>>(x, A, W, b, y, part, counter);
  k2_stats<<<64, 256, 0, stream>>>(part, gamma, beta, ss);
  k3_finish<<<4096, 256, 0, stream>>>(x, ss, y);
}